// Round 6
// baseline (150.506 us; speedup 1.0000x reference)
//
#include <hip/hip_runtime.h>
#include <hip/hip_bf16.h>

// TTT-MLP, round 6.  out = LN( h @ Weq^T + beq ),  h = relu(x@W1^T + b1),
// Weq = Wo@W2, beq = Wo@b2 + bo  (TTT inner loop never updates weights).
// New: G1 fuses the fp32->bf16 cast of x into its LDS staging (fp32 A-tiles
// via global_load_lds, convert at fragment read), with a 3-buffer depth-2
// counted-vmcnt pipeline. G2 = proven 2-phase 128^2 dbuf. prep = weights only.

#define HIDDEN 768
#define INNER  512

typedef __bf16 bf16_t;
typedef bf16_t bf16x8 __attribute__((ext_vector_type(8)));
typedef bf16_t bf16x4 __attribute__((ext_vector_type(4)));
typedef float  f32x4  __attribute__((ext_vector_type(4)));

__device__ __forceinline__ void async16(const void* g, void* lds) {
  __builtin_amdgcn_global_load_lds(
      (const __attribute__((address_space(1))) unsigned int*)g,
      (__attribute__((address_space(3))) unsigned int*)lds, 16, 0, 0);
}

// ---------------------------------------------------------------- prep: weight casts + W2 transpose
// blocks [0,24): W1 cast ; [24,60): Wo cast ; [60,156): W2 -> W2t (bf16, transposed)
__global__ __launch_bounds__(256)
void prep(const float* __restrict__ W1, const float* __restrict__ W2,
          const float* __restrict__ Wo, bf16_t* __restrict__ W1b,
          bf16_t* __restrict__ W2t, bf16_t* __restrict__ Wob) {
  __shared__ float T[64][65];
  const int b = blockIdx.x, t = threadIdx.x;

  const float4* src; bf16x4* dst; int base;
  if (b < 24)       { src = (const float4*)W1; dst = (bf16x4*)W1b; base = b * 4096; }
  else if (b < 60)  { src = (const float4*)Wo; dst = (bf16x4*)Wob; base = (b - 24) * 4096; }
  else {
    // W2 [768,512] -> W2t [512,768], 64x64 tile per block (96 tiles)
    const int tile = b - 60;
    const int d0 = (tile >> 3) << 6;
    const int i0 = (tile & 7) << 6;
#pragma unroll
    for (int j = 0; j < 4; ++j) {
      const int idx = j * 256 + t;
      const int r = idx >> 4, c4 = idx & 15;
      float4 v = *(const float4*)(W2 + (size_t)(d0 + r) * INNER + i0 + c4 * 4);
      T[r][c4 * 4 + 0] = v.x; T[r][c4 * 4 + 1] = v.y;
      T[r][c4 * 4 + 2] = v.z; T[r][c4 * 4 + 3] = v.w;
    }
    __syncthreads();
    const int i = t & 63, h4 = t >> 6;
    bf16x8 o0, o1;
#pragma unroll
    for (int c = 0; c < 8; ++c) { o0[c] = (bf16_t)T[h4 * 16 + c][i]; o1[c] = (bf16_t)T[h4 * 16 + 8 + c][i]; }
    bf16_t* orow = W2t + (size_t)(i0 + i) * HIDDEN + d0 + h4 * 16;
    *(bf16x8*)orow = o0;
    *(bf16x8*)(orow + 8) = o1;
    return;
  }
#pragma unroll
  for (int i = 0; i < 16; ++i) {
    float4 v = src[base + i * 256 + t];
    bf16x4 o;
    o[0] = (bf16_t)v.x; o[1] = (bf16_t)v.y; o[2] = (bf16_t)v.z; o[3] = (bf16_t)v.w;
    dst[base + i * 256 + t] = o;
  }
}

// ---------------------------------------------------------------- beq = Wo @ b2 + bo
__global__ __launch_bounds__(256)
void beq_k(const float* __restrict__ Wo, const float* __restrict__ b2,
           const float* __restrict__ bo, float* __restrict__ beq) {
  const int e = blockIdx.x * 4 + (threadIdx.x >> 6);
  const int l = threadIdx.x & 63;
  float s = 0.f;
#pragma unroll
  for (int j = 0; j < 12; ++j) s += Wo[(size_t)e * HIDDEN + j * 64 + l] * b2[j * 64 + l];
#pragma unroll
  for (int off = 1; off < 64; off <<= 1) s += __shfl_xor(s, off, 64);
  if (l == 0) beq[e] = s + bo[e];
}

// ---------------------------------------------------------------- G1 fused: h = relu(x@W1^T + b1)
// A = x fp32, staged via async16 into fp32 LDS (swizzled), cvt at fragment read.
// 128x128 tile, BK=64, 4 waves (2x2). 3-buffer depth-2 counted-vmcnt pipeline.
__global__ __launch_bounds__(256, 1)
void gemm1_fused(const float* __restrict__ x, const bf16_t* __restrict__ W1b,
                 const float* __restrict__ b1, bf16_t* __restrict__ h) {
  constexpr int T = HIDDEN / 64;                     // 12 K-tiles
  __shared__ __align__(16) float  Af[3][128 * 64];   // 3 x 32 KB fp32
  __shared__ __align__(16) bf16_t Bs[3][128 * 64];   // 3 x 16 KB bf16

  const int per = gridDim.x >> 3;                    // grid = 1024, %8==0
  const int nb  = (blockIdx.x & 7) * per + (blockIdx.x >> 3);
  const int m0  = (nb >> 2) * 128;                   // N=512 -> 4 col-tiles
  const int n0  = (nb & 3) * 128;

  const int tid = threadIdx.x;
  const int w = tid >> 6, l = tid & 63;
  const int wr = w >> 1, wc = w & 1;
  const int fr = l & 15, fq = l >> 4;

  // A: 128 rows x 16 granules(16B) of fp32; LDS linear, source XOR-swizzled g^(row&15)
#define STAGE_A(buf, k0)                                                      \
  _Pragma("unroll") for (int i = 0; i < 8; ++i) {                             \
    const int G = i * 256 + tid, row = G >> 4, g = G & 15;                    \
    async16(x + (size_t)(m0 + row) * HIDDEN + (k0) + ((g ^ (row & 15)) << 2), \
            (char*)Af[buf] + (size_t)(i * 256 + w * 64) * 16);                \
  }
  // B: 128 rows x 8 granules of bf16; source XOR-swizzled g^(row&7)
#define STAGE_B(buf, k0)                                                      \
  _Pragma("unroll") for (int i = 0; i < 4; ++i) {                             \
    const int G = i * 256 + tid, row = G >> 3, g = G & 7;                     \
    async16(W1b + (size_t)(n0 + row) * HIDDEN + (k0) + ((g ^ (row & 7)) << 3),\
            (char*)Bs[buf] + (size_t)(i * 256 + w * 64) * 16);                \
  }

  STAGE_A(0, 0);  STAGE_B(0, 0);                     // 12 loads (tile 0)
  STAGE_A(1, 64); STAGE_B(1, 64);                    // +12   (tile 1)
  asm volatile("s_waitcnt vmcnt(12)" ::: "memory");  // tile 0 landed
  __builtin_amdgcn_s_barrier();

  f32x4 acc[4][4] = {};
#pragma unroll
  for (int t = 0; t < T; ++t) {
    const int cur = t % 3;
    if (t + 2 < T) {                                 // buffer (t+2)%3 last read at t-1
      const int nx = (t + 2) % 3;
      STAGE_A(nx, (t + 2) * 64);
      STAGE_B(nx, (t + 2) * 64);
    }
    __builtin_amdgcn_s_setprio(1);
#pragma unroll
    for (int kk = 0; kk < 2; ++kk) {
      bf16x8 ax[4], bx[4];
#pragma unroll
      for (int m = 0; m < 4; ++m) {
        const int row = wr * 64 + m * 16 + fr;
        const int c0 = kk * 8 + fq * 2;              // logical granule pair
        const int s0 = c0 ^ (row & 15), s1 = (c0 + 1) ^ (row & 15);
        f32x4 p0 = *(const f32x4*)(Af[cur] + row * 64 + s0 * 4);
        f32x4 p1 = *(const f32x4*)(Af[cur] + row * 64 + s1 * 4);
        bf16x8 a;
#pragma unroll
        for (int c = 0; c < 4; ++c) { a[c] = (bf16_t)p0[c]; a[4 + c] = (bf16_t)p1[c]; }
        ax[m] = a;
      }
#pragma unroll
      for (int n = 0; n < 4; ++n) {
        const int row = wc * 64 + n * 16 + fr;
        const int slot = (kk * 4 + fq) ^ (row & 7);
        bx[n] = *(const bf16x8*)((const char*)Bs[cur] + row * 128 + slot * 16);
      }
#pragma unroll
      for (int m = 0; m < 4; ++m)
#pragma unroll
        for (int n = 0; n < 4; ++n)
          acc[m][n] = __builtin_amdgcn_mfma_f32_16x16x32_bf16(ax[m], bx[n], acc[m][n], 0, 0, 0);
    }
    __builtin_amdgcn_s_setprio(0);
    if (t < T - 1) {
      if (t + 2 < T) asm volatile("s_waitcnt vmcnt(12)" ::: "memory");  // tile t+1 landed
      else           asm volatile("s_waitcnt vmcnt(0)"  ::: "memory");
      __builtin_amdgcn_s_barrier();
    }
  }
#undef STAGE_A
#undef STAGE_B

  const int orow0 = m0 + wr * 64 + fq * 4;
  const int ocol0 = n0 + wc * 64 + fr;
#pragma unroll
  for (int n = 0; n < 4; ++n) {
    const int col = ocol0 + n * 16;
    const float bv = b1[col];
#pragma unroll
    for (int m = 0; m < 4; ++m)
#pragma unroll
      for (int j = 0; j < 4; ++j)
        h[(size_t)(orow0 + m * 16 + j) * INNER + col] = (bf16_t)fmaxf(acc[m][n][j] + bv, 0.f);
  }
}

// ---------------------------------------------------------------- GEMM (A[M,K] x Bt[N,K]) -> bf16
// 2-phase dbuf 128^2, 2 blocks/CU (round-4 proven). MODE 1: +bias ; MODE 2: plain.
template <int N_, int K_, int MODE>
__global__ __launch_bounds__(256, 2)
void gemm_bt(const bf16_t* __restrict__ A, const bf16_t* __restrict__ Bt,
             const float* __restrict__ bias, bf16_t* __restrict__ Cout) {
  constexpr int NT = N_ / 128;
  constexpr int T  = K_ / 64;
  __shared__ __align__(16) bf16_t As[2][128 * 64];
  __shared__ __align__(16) bf16_t Bs[2][128 * 64];

  const int per = gridDim.x >> 3;
  const int nb  = (blockIdx.x & 7) * per + (blockIdx.x >> 3);
  const int m0 = (nb / NT) * 128;
  const int n0 = (nb % NT) * 128;

  const int tid = threadIdx.x;
  const int w = tid >> 6, l = tid & 63;
  const int wr = w >> 1, wc = w & 1;
  const int fr = l & 15, fq = l >> 4;

#define STAGE(dst, src, r0, k0)                                               \
  _Pragma("unroll") for (int i = 0; i < 4; ++i) {                             \
    const int G = i * 256 + tid, row = G >> 3, g = G & 7;                     \
    async16((src) + (size_t)((r0) + row) * K_ + (k0) + ((g ^ (row & 7)) << 3),\
            (char*)(dst) + (size_t)(i * 256 + w * 64) * 16);                  \
  }

  STAGE(As[0], A, m0, 0); STAGE(Bs[0], Bt, n0, 0);
  __syncthreads();

  f32x4 acc[4][4] = {};
#pragma unroll
  for (int t = 0; t < T; ++t) {
    const int cur = t & 1;
    if (t < T - 1) {
      STAGE(As[cur ^ 1], A, m0, (t + 1) * 64);
      STAGE(Bs[cur ^ 1], Bt, n0, (t + 1) * 64);
    }
#pragma unroll
    for (int kk = 0; kk < 2; ++kk) {
      bf16x8 ax[4], bx[4];
#pragma unroll
      for (int m = 0; m < 4; ++m) {
        const int row = wr * 64 + m * 16 + fr;
        const int slot = (kk * 4 + fq) ^ (row & 7);
        ax[m] = *(const bf16x8*)((const char*)As[cur] + row * 128 + slot * 16);
      }
#pragma unroll
      for (int n = 0; n < 4; ++n) {
        const int row = wc * 64 + n * 16 + fr;
        const int slot = (kk * 4 + fq) ^ (row & 7);
        bx[n] = *(const bf16x8*)((const char*)Bs[cur] + row * 128 + slot * 16);
      }
#pragma unroll
      for (int m = 0; m < 4; ++m)
#pragma unroll
        for (int n = 0; n < 4; ++n)
          acc[m][n] = __builtin_amdgcn_mfma_f32_16x16x32_bf16(ax[m], bx[n], acc[m][n], 0, 0, 0);
    }
    __syncthreads();
  }
#undef STAGE

  const int orow0 = m0 + wr * 64 + fq * 4;
  const int ocol0 = n0 + wc * 64 + fr;
#pragma unroll
  for (int n = 0; n < 4; ++n) {
    const int col = ocol0 + n * 16;
    const float bv = (MODE == 2) ? 0.f : bias[col];
#pragma unroll
    for (int m = 0; m < 4; ++m)
#pragma unroll
      for (int j = 0; j < 4; ++j)
        Cout[(size_t)(orow0 + m * 16 + j) * N_ + col] = (bf16_t)(acc[m][n][j] + bv);
  }
}

// ---------------------------------------------------------------- LN: bf16 raw -> fp32 out
__global__ __launch_bounds__(256)
void ln_bf16(const bf16_t* __restrict__ raw, const float* __restrict__ gamma,
             const float* __restrict__ beta, float* __restrict__ out) {
  const int r = blockIdx.x * 4 + (threadIdx.x >> 6);
  const int l = threadIdx.x & 63;
  const bf16_t* rp = raw + (size_t)r * HIDDEN;
  float v[12];
  float s = 0.f, q = 0.f;
#pragma unroll
  for (int c = 0; c < 3; ++c) {
    bf16x4 b4 = *(const bf16x4*)(rp + c * 256 + l * 4);
#pragma unroll
    for (int j = 0; j < 4; ++j) {
      const float f = (float)b4[j];
      v[c * 4 + j] = f; s += f; q += f * f;
    }
  }
#pragma unroll
  for (int off = 1; off < 64; off <<= 1) {
    s += __shfl_xor(s, off, 64);
    q += __shfl_xor(q, off, 64);
  }
  const float mu  = s * (1.0f / HIDDEN);
  const float var = fmaxf(q * (1.0f / HIDDEN) - mu * mu, 0.f);
  const float inv = rsqrtf(var + 1e-5f);
  float* op = out + (size_t)r * HIDDEN;
#pragma unroll
  for (int c = 0; c < 3; ++c) {
    float4 g = ((const float4*)gamma)[c * 64 + l];
    float4 b = ((const float4*)beta)[c * 64 + l];
    float4 o;
    o.x = (v[c * 4 + 0] - mu) * inv * g.x + b.x;
    o.y = (v[c * 4 + 1] - mu) * inv * g.y + b.y;
    o.z = (v[c * 4 + 2] - mu) * inv * g.z + b.z;
    o.w = (v[c * 4 + 3] - mu) * inv * g.w + b.w;
    ((float4*)op)[c * 64 + l] = o;
  }
}

// ---------------------------------------------------------------- launch
extern "C" void kernel_launch(void* const* d_in, const int* in_sizes, int n_in,
                              void* d_out, int out_size, void* d_ws, size_t ws_size,
                              hipStream_t stream) {
  const float* x     = (const float*)d_in[0];
  const float* W1    = (const float*)d_in[1];
  const float* b1    = (const float*)d_in[2];
  const float* W2    = (const float*)d_in[3];
  const float* b2    = (const float*)d_in[4];
  const float* Wo    = (const float*)d_in[5];
  const float* bo    = (const float*)d_in[6];
  const float* gamma = (const float*)d_in[7];
  const float* beta  = (const float*)d_in[8];

  const int M = in_sizes[0] / HIDDEN;   // 32768 tokens

  // ws: raw (bf16 M*768) | h (bf16 M*512) | W1b | W2t | Wob | Weq | beq
  char* ws = (char*)d_ws;
  bf16_t* raw  = (bf16_t*)ws;
  bf16_t* h    = (bf16_t*)(ws + (size_t)M * HIDDEN * 2);
  bf16_t* W1b  = (bf16_t*)(ws + (size_t)M * HIDDEN * 2 + (size_t)M * INNER * 2);
  bf16_t* W2t  = W1b + INNER * HIDDEN;                   // [512,768]
  bf16_t* Wob  = W2t + INNER * HIDDEN;                   // [768,768]
  bf16_t* Weq  = Wob + HIDDEN * HIDDEN;                  // [768,512]
  float*  beq  = (float*)(Weq + HIDDEN * INNER);

  prep<<<156, 256, 0, stream>>>(W1, W2, Wo, W1b, W2t, Wob);
  beq_k<<<HIDDEN / 4, 256, 0, stream>>>(Wo, b2, bo, beq);

  // Weq = Wo @ W2 : A=Wob [768,768], Bt=W2t [512,768] -> [768,512]
  gemm_bt<INNER, HIDDEN, 2><<<(HIDDEN / 128) * (INNER / 128), 256, 0, stream>>>(Wob, W2t, nullptr, Weq);
  // h = relu(x @ W1^T + b1)   (fp32 x staged directly, cast in-kernel)
  gemm1_fused<<<(M / 128) * (INNER / 128), 256, 0, stream>>>(x, W1b, b1, h);
  // raw = h @ Weq^T + beq
  gemm_bt<HIDDEN, INNER, 1><<<(M / 128) * (HIDDEN / 128), 256, 0, stream>>>(h, Weq, beq, raw);
  // out = LN(raw)
  ln_bf16<<<M / 4, 256, 0, stream>>>(raw, gamma, beta, (float*)d_out);
}

// Round 7
// 134.579 us; speedup vs baseline: 1.1183x; 1.1183x over previous
//
#include <hip/hip_runtime.h>
#include <hip/hip_bf16.h>

// TTT-MLP, round 7: single mega-kernel per 64-token strip.
//   out = LN( h @ Weq^T + beq ),  h = relu(x@W1^T + b1)   [Weq = Wo@W2, beq = Wo@b2+bo]
// Phase 1: x (fp32, HBM) staged direct -> LDS, cast at frag read; W1 streamed;
//          h written to LDS only (never HBM).
// Phase 2: raw = h(LDS) @ Weq^T streamed; LN fused in epilogue (row in-block).
// LDS 152 KB, 512 threads (8 waves, 2m x 4n), 1 block/CU, grid = M/64 = 512.

#define HIDDEN 768
#define INNER  512

typedef __bf16 bf16_t;
typedef bf16_t bf16x8 __attribute__((ext_vector_type(8)));
typedef bf16_t bf16x4 __attribute__((ext_vector_type(4)));
typedef float  f32x4  __attribute__((ext_vector_type(4)));

__device__ __forceinline__ void async16(const void* g, void* lds) {
  __builtin_amdgcn_global_load_lds(
      (const __attribute__((address_space(1))) unsigned int*)g,
      (__attribute__((address_space(3))) unsigned int*)lds, 16, 0, 0);
}

// ---------------------------------------------------------------- prep: weight casts + W2 transpose
__global__ __launch_bounds__(256)
void prep(const float* __restrict__ W1, const float* __restrict__ W2,
          const float* __restrict__ Wo, bf16_t* __restrict__ W1b,
          bf16_t* __restrict__ W2t, bf16_t* __restrict__ Wob) {
  __shared__ float T[64][65];
  const int b = blockIdx.x, t = threadIdx.x;

  const float4* src; bf16x4* dst; int base;
  if (b < 24)       { src = (const float4*)W1; dst = (bf16x4*)W1b; base = b * 4096; }
  else if (b < 60)  { src = (const float4*)Wo; dst = (bf16x4*)Wob; base = (b - 24) * 4096; }
  else {
    const int tile = b - 60;
    const int d0 = (tile >> 3) << 6;
    const int i0 = (tile & 7) << 6;
#pragma unroll
    for (int j = 0; j < 4; ++j) {
      const int idx = j * 256 + t;
      const int r = idx >> 4, c4 = idx & 15;
      float4 v = *(const float4*)(W2 + (size_t)(d0 + r) * INNER + i0 + c4 * 4);
      T[r][c4 * 4 + 0] = v.x; T[r][c4 * 4 + 1] = v.y;
      T[r][c4 * 4 + 2] = v.z; T[r][c4 * 4 + 3] = v.w;
    }
    __syncthreads();
    const int i = t & 63, h4 = t >> 6;
    bf16x8 o0, o1;
#pragma unroll
    for (int c = 0; c < 8; ++c) { o0[c] = (bf16_t)T[h4 * 16 + c][i]; o1[c] = (bf16_t)T[h4 * 16 + 8 + c][i]; }
    bf16_t* orow = W2t + (size_t)(i0 + i) * HIDDEN + d0 + h4 * 16;
    *(bf16x8*)orow = o0;
    *(bf16x8*)(orow + 8) = o1;
    return;
  }
#pragma unroll
  for (int i = 0; i < 16; ++i) {
    float4 v = src[base + i * 256 + t];
    bf16x4 o;
    o[0] = (bf16_t)v.x; o[1] = (bf16_t)v.y; o[2] = (bf16_t)v.z; o[3] = (bf16_t)v.w;
    dst[base + i * 256 + t] = o;
  }
}

// ---------------------------------------------------------------- beq = Wo @ b2 + bo
__global__ __launch_bounds__(256)
void beq_k(const float* __restrict__ Wo, const float* __restrict__ b2,
           const float* __restrict__ bo, float* __restrict__ beq) {
  const int e = blockIdx.x * 4 + (threadIdx.x >> 6);
  const int l = threadIdx.x & 63;
  float s = 0.f;
#pragma unroll
  for (int j = 0; j < 12; ++j) s += Wo[(size_t)e * HIDDEN + j * 64 + l] * b2[j * 64 + l];
#pragma unroll
  for (int off = 1; off < 64; off <<= 1) s += __shfl_xor(s, off, 64);
  if (l == 0) beq[e] = s + bo[e];
}

// ---------------------------------------------------------------- Weq = Wo @ W2 (2-phase 128^2)
__global__ __launch_bounds__(256, 2)
void gemm_weq(const bf16_t* __restrict__ A, const bf16_t* __restrict__ Bt,
              bf16_t* __restrict__ Cout) {
  constexpr int N_ = INNER, K_ = HIDDEN, NT = N_ / 128, T = K_ / 64;
  __shared__ __align__(16) bf16_t As[2][128 * 64];
  __shared__ __align__(16) bf16_t Bs[2][128 * 64];

  const int nb = blockIdx.x;
  const int m0 = (nb / NT) * 128;
  const int n0 = (nb % NT) * 128;

  const int tid = threadIdx.x;
  const int w = tid >> 6, l = tid & 63;
  const int wr = w >> 1, wc = w & 1;
  const int fr = l & 15, fq = l >> 4;

#define STAGEW(dst, src, r0, k0)                                              \
  _Pragma("unroll") for (int i = 0; i < 4; ++i) {                             \
    const int G = i * 256 + tid, row = G >> 3, g = G & 7;                     \
    async16((src) + (size_t)((r0) + row) * K_ + (k0) + ((g ^ (row & 7)) << 3),\
            (char*)(dst) + (size_t)(i * 256 + w * 64) * 16);                  \
  }

  STAGEW(As[0], A, m0, 0); STAGEW(Bs[0], Bt, n0, 0);
  __syncthreads();

  f32x4 acc[4][4] = {};
#pragma unroll
  for (int t = 0; t < T; ++t) {
    const int cur = t & 1;
    if (t < T - 1) {
      STAGEW(As[cur ^ 1], A, m0, (t + 1) * 64);
      STAGEW(Bs[cur ^ 1], Bt, n0, (t + 1) * 64);
    }
#pragma unroll
    for (int kk = 0; kk < 2; ++kk) {
      bf16x8 ax[4], bx[4];
#pragma unroll
      for (int m = 0; m < 4; ++m) {
        const int row = wr * 64 + m * 16 + fr;
        const int slot = (kk * 4 + fq) ^ (row & 7);
        ax[m] = *(const bf16x8*)((const char*)As[cur] + row * 128 + slot * 16);
      }
#pragma unroll
      for (int n = 0; n < 4; ++n) {
        const int row = wc * 64 + n * 16 + fr;
        const int slot = (kk * 4 + fq) ^ (row & 7);
        bx[n] = *(const bf16x8*)((const char*)Bs[cur] + row * 128 + slot * 16);
      }
#pragma unroll
      for (int m = 0; m < 4; ++m)
#pragma unroll
        for (int n = 0; n < 4; ++n)
          acc[m][n] = __builtin_amdgcn_mfma_f32_16x16x32_bf16(ax[m], bx[n], acc[m][n], 0, 0, 0);
    }
    __syncthreads();
  }
#undef STAGEW

  const int orow0 = m0 + wr * 64 + fq * 4;
  const int ocol0 = n0 + wc * 64 + fr;
#pragma unroll
  for (int n = 0; n < 4; ++n)
#pragma unroll
    for (int m = 0; m < 4; ++m)
#pragma unroll
      for (int j = 0; j < 4; ++j)
        Cout[(size_t)(orow0 + m * 16 + j) * N_ + ocol0 + n * 16] = (bf16_t)acc[m][n][j];
}

// ---------------------------------------------------------------- MEGA
// LDS map (byte offsets in L):
//   [0, 64K)          hS [64][512] bf16, granule-swizzled g^(row&7)   (later: snorm[2][64])
//   [64K, 64K+24K)    A1: 3 x 8KB fp32 x-tiles [64][32], swizzle g^(row&7)
//   [88K, 88K+64K)    B1: 2 x 32KB W1 tiles [512][32], swizzle g^(row&3)^((row&4)>>1)
//   phase 2 overlays [64K, 64K+48K) with B2: Weq tile [768][32], same swizzle class
__global__ __launch_bounds__(512, 1)
void mega(const float* __restrict__ x, const bf16_t* __restrict__ W1b,
          const float* __restrict__ b1, const bf16_t* __restrict__ Weq,
          const float* __restrict__ beq, const float* __restrict__ gamma,
          const float* __restrict__ beta, float* __restrict__ out) {
  __shared__ __align__(16) char L[155648];
  char* hS = L;
  char* A1 = L + 65536;
  char* B1 = L + 65536 + 24576;
  char* B2 = L + 65536;
  float* sn = (float*)L;                       // [2][64] after phase-2 compute

  const int tid = threadIdx.x;
  const int w = tid >> 6, l = tid & 63;
  const int wm = w >> 2, wn = w & 3;           // 2m x 4n wave grid
  const int fr = l & 15, fq = l >> 4;
  const int gm0 = blockIdx.x * 64;

  // ---------------- phase 1: h = relu(x @ W1^T + b1) -> hS
#define STAGE_A1(buf, k0) {                                                   \
    const int row = tid >> 3, g = tid & 7;                                    \
    async16(x + (size_t)(gm0 + row) * HIDDEN + (k0) + ((g ^ (row & 7)) << 2), \
            A1 + (buf) * 8192 + tid * 16);                                    \
  }
#define STAGE_B1(buf, k0)                                                     \
  _Pragma("unroll") for (int i = 0; i < 4; ++i) {                             \
    const int G = i * 512 + tid, row = G >> 2, g = G & 3;                     \
    const int sl = g ^ (row & 3) ^ ((row & 4) >> 1);                          \
    async16(W1b + (size_t)row * HIDDEN + (k0) + (sl << 3),                    \
            B1 + (buf) * 32768 + G * 16);                                     \
  }

  STAGE_B1(0, 0);
  STAGE_A1(0, 0);
  STAGE_A1(1, 32);
  asm volatile("s_waitcnt vmcnt(1)" ::: "memory");   // B(0)+A(0) landed; A(1) in flight
  __builtin_amdgcn_s_barrier();

  f32x4 acc1[2][8] = {};
#pragma unroll 6
  for (int t = 0; t < 24; ++t) {
    if (t + 1 < 24) STAGE_B1((t + 1) & 1, (t + 1) * 32);
    if (t + 2 < 24) STAGE_A1((t + 2) % 3, (t + 2) * 32);
    const char* Ab = A1 + (t % 3) * 8192;
    const char* Bb = B1 + (t & 1) * 32768;
    __builtin_amdgcn_s_setprio(1);
    bf16x8 ax[2];
#pragma unroll
    for (int m = 0; m < 2; ++m) {
      const int row = wm * 32 + m * 16 + fr;
      const int p0 = (2 * fq) ^ (row & 7), p1 = (2 * fq + 1) ^ (row & 7);
      f32x4 q0 = *(const f32x4*)(Ab + row * 128 + p0 * 16);
      f32x4 q1 = *(const f32x4*)(Ab + row * 128 + p1 * 16);
      bf16x8 a;
#pragma unroll
      for (int c = 0; c < 4; ++c) { a[c] = (bf16_t)q0[c]; a[4 + c] = (bf16_t)q1[c]; }
      ax[m] = a;
    }
#pragma unroll
    for (int n = 0; n < 8; ++n) {
      const int row = wn * 128 + n * 16 + fr;
      const int sl = fq ^ (row & 3) ^ ((row & 4) >> 1);
      bf16x8 bx = *(const bf16x8*)(Bb + row * 64 + sl * 16);
#pragma unroll
      for (int m = 0; m < 2; ++m)
        acc1[m][n] = __builtin_amdgcn_mfma_f32_16x16x32_bf16(ax[m], bx, acc1[m][n], 0, 0, 0);
    }
    __builtin_amdgcn_s_setprio(0);
    if (t < 23) {
      if (t + 2 < 24) asm volatile("s_waitcnt vmcnt(1)" ::: "memory");
      else            asm volatile("s_waitcnt vmcnt(0)" ::: "memory");
      __builtin_amdgcn_s_barrier();
    }
  }
#undef STAGE_A1
#undef STAGE_B1

  // epilogue 1: bias + relu -> hS (swizzled)
#pragma unroll
  for (int n = 0; n < 8; ++n) {
    const int col = wn * 128 + n * 16 + fr;
    const float bv = b1[col];
    const int g0 = col >> 3, b2c = (col & 7) * 2;
#pragma unroll
    for (int m = 0; m < 2; ++m)
#pragma unroll
      for (int j = 0; j < 4; ++j) {
        const int row = wm * 32 + m * 16 + fq * 4 + j;
        *(bf16_t*)(hS + row * 1024 + (g0 ^ (row & 7)) * 16 + b2c) =
            (bf16_t)fmaxf(acc1[m][n][j] + bv, 0.f);
      }
  }
  __syncthreads();

  // ---------------- phase 2: raw = h @ Weq^T (+beq), LN fused
  f32x4 acc2[2][12] = {};
#pragma unroll 2
  for (int t = 0; t < 16; ++t) {
#pragma unroll
    for (int i = 0; i < 6; ++i) {                    // stage Weq [768][32] tile
      const int G = i * 512 + tid, row = G >> 2, g = G & 3;
      const int sl = g ^ (row & 3) ^ ((row & 4) >> 1);
      async16(Weq + (size_t)row * INNER + t * 32 + (sl << 3), B2 + G * 16);
    }
    __syncthreads();                                 // drains vmcnt before barrier
    __builtin_amdgcn_s_setprio(1);
    bf16x8 ax[2];
#pragma unroll
    for (int m = 0; m < 2; ++m) {
      const int row = wm * 32 + m * 16 + fr;
      const int g = t * 4 + fq;
      ax[m] = *(const bf16x8*)(hS + row * 1024 + (g ^ (row & 7)) * 16);
    }
#pragma unroll
    for (int n = 0; n < 12; ++n) {
      const int row = wn * 192 + n * 16 + fr;
      const int sl = fq ^ (row & 3) ^ ((row & 4) >> 1);
      bf16x8 bx = *(const bf16x8*)(B2 + row * 64 + sl * 16);
#pragma unroll
      for (int m = 0; m < 2; ++m)
        acc2[m][n] = __builtin_amdgcn_mfma_f32_16x16x32_bf16(ax[m], bx, acc2[m][n], 0, 0, 0);
    }
    __builtin_amdgcn_s_setprio(0);
    __syncthreads();
  }

  // fold beq, row stats (sum, sumsq) via fr-shfl + LDS atomics
  if (tid < 128) sn[tid] = 0.f;
  __syncthreads();
#pragma unroll
  for (int n = 0; n < 12; ++n) {
    const float bv = beq[wn * 192 + n * 16 + fr];
#pragma unroll
    for (int m = 0; m < 2; ++m)
#pragma unroll
      for (int j = 0; j < 4; ++j) acc2[m][n][j] += bv;
  }
#pragma unroll
  for (int m = 0; m < 2; ++m)
#pragma unroll
    for (int j = 0; j < 4; ++j) {
      float s = 0.f, q = 0.f;
#pragma unroll
      for (int n = 0; n < 12; ++n) {
        const float v = acc2[m][n][j];
        s += v; q += v * v;
      }
#pragma unroll
      for (int off = 1; off < 16; off <<= 1) {
        s += __shfl_xor(s, off, 64);
        q += __shfl_xor(q, off, 64);
      }
      if (fr == 0) {
        const int row = wm * 32 + m * 16 + fq * 4 + j;
        atomicAdd(&sn[row], s);
        atomicAdd(&sn[64 + row], q);
      }
    }
  __syncthreads();

  // normalize + write fp32 out
  float gv[12], bw[12];
#pragma unroll
  for (int n = 0; n < 12; ++n) {
    const int col = wn * 192 + n * 16 + fr;
    gv[n] = gamma[col]; bw[n] = beta[col];
  }
#pragma unroll
  for (int m = 0; m < 2; ++m)
#pragma unroll
    for (int j = 0; j < 4; ++j) {
      const int row = wm * 32 + m * 16 + fq * 4 + j;
      const float mu  = sn[row] * (1.0f / HIDDEN);
      const float var = fmaxf(sn[64 + row] * (1.0f / HIDDEN) - mu * mu, 0.f);
      const float inv = rsqrtf(var + 1e-5f);
      float* orow = out + (size_t)(gm0 + row) * HIDDEN;
#pragma unroll
      for (int n = 0; n < 12; ++n)
        orow[wn * 192 + n * 16 + fr] = (acc2[m][n][j] - mu) * inv * gv[n] + bw[n];
    }
}

// ---------------------------------------------------------------- launch
extern "C" void kernel_launch(void* const* d_in, const int* in_sizes, int n_in,
                              void* d_out, int out_size, void* d_ws, size_t ws_size,
                              hipStream_t stream) {
  const float* x     = (const float*)d_in[0];
  const float* W1    = (const float*)d_in[1];
  const float* b1    = (const float*)d_in[2];
  const float* W2    = (const float*)d_in[3];
  const float* b2    = (const float*)d_in[4];
  const float* Wo    = (const float*)d_in[5];
  const float* bo    = (const float*)d_in[6];
  const float* gamma = (const float*)d_in[7];
  const float* beta  = (const float*)d_in[8];

  const int M = in_sizes[0] / HIDDEN;   // 32768 tokens

  // ws: W1b | W2t | Wob | Weq | beq   (~3.5 MB)
  char* ws = (char*)d_ws;
  bf16_t* W1b = (bf16_t*)ws;                            // [512,768]
  bf16_t* W2t = W1b + INNER * HIDDEN;                   // [512,768]
  bf16_t* Wob = W2t + INNER * HIDDEN;                   // [768,768]
  bf16_t* Weq = Wob + HIDDEN * HIDDEN;                  // [768,512]
  float*  beq = (float*)(Weq + HIDDEN * INNER);

  prep<<<156, 256, 0, stream>>>(W1, W2, Wo, W1b, W2t, Wob);
  beq_k<<<HIDDEN / 4, 256, 0, stream>>>(Wo, b2, bo, beq);
  gemm_weq<<<(HIDDEN / 128) * (INNER / 128), 256, 0, stream>>>(Wob, W2t, Weq);
  mega<<<M / 64, 512, 0, stream>>>(x, W1b, b1, Weq, beq, gamma, beta, (float*)d_out);
}